// Round 1
// baseline (189071.399 us; speedup 1.0000x reference)
//
#include <hip/hip_runtime.h>
#include <hip/hip_cooperative_groups.h>
#include <math.h>

namespace cg = cooperative_groups;

#define NBATCH 8      // B
#define BW     64     // W (block width)
#define DIMD   1024   // DIM
#define NB     512    // number of blocks (N / W)
#define NH     16384  // Nh
#define NITERS 10
#define NWG    64     // workgroups
#define NT     256    // threads per workgroup

// Workspace layout (floats):
//  [0 .. 16383]          x as float2[8192]  (b*1024 + d)
//  [16384 .. 17407]      r as float2[512]   (b*64 + w)
//  [17408 .. 17471]      per-WG partial max (64)
//  [17472 .. 279615]     tau [blk][b][w]    (512*8*64)
// Total ~1.07 MB.

__launch_bounds__(NT, 1)
__global__ void robii_kernel(
    const float* __restrict__ y_re, const float* __restrict__ y_im,
    const float* __restrict__ H_re, const float* __restrict__ H_im,
    const float* __restrict__ estep_w, const float* __restrict__ estep_b,
    const float* __restrict__ update_w, const float* __restrict__ update_b,
    const float* __restrict__ memory_w, const float* __restrict__ memory_b,
    float* __restrict__ out, float* __restrict__ ws)
{
    cg::grid_group grid = cg::this_grid();

    __shared__ float wTe[64 * 64];   // transposed: wTe[k*64+j] = estep_w[j*64+k]
    __shared__ float wTu[64 * 64];
    __shared__ float wTm[64 * 64];
    __shared__ float be[64], bu[64], bm[64];
    __shared__ float2 rl[512];       // r values (b*64+w)
    __shared__ float a2s[512];
    __shared__ float red[NT];
    __shared__ float xts[64], hts[64], taurow[64];
    __shared__ float2 resid[64];
    __shared__ float2 cpart[128];

    const int g = blockIdx.x;
    const int t = threadIdx.x;
    const int b = g >> 3;            // batch this WG owns for B/C phases
    const int chunk = g & 7;         // d-chunk (128 wide) this WG owns
    const int w0 = (g & 7) * 8;      // w-range start for phase A
    const int wave = t >> 6;
    const int lane = t & 63;

    float2* xg  = (float2*)ws;                  // 8192 float2
    float2* rg  = (float2*)(ws + 16384);        // 512 float2
    float*  pm  = ws + 17408;                   // 64 floats
    float*  taug = ws + 17472;                  // 262144 floats

    // ---- load weights (transposed) into LDS ----
    for (int idx = t; idx < 4096; idx += NT) {
        int j = idx >> 6, k = idx & 63;
        wTe[k * 64 + j] = estep_w[idx];
        wTu[k * 64 + j] = update_w[idx];
        wTm[k * 64 + j] = memory_w[idx];
    }
    if (t < 64) { be[t] = estep_b[t]; bu[t] = update_b[t]; bm[t] = memory_b[t]; }

    // ---- init workspace: x = 0 (own chunk), tau = 1 (own slice) ----
    if (t < 128) xg[b * 1024 + chunk * 128 + t] = make_float2(0.0f, 0.0f);
    for (int idx = t; idx < 4096; idx += NT) taug[g * 4096 + idx] = 1.0f;
    __syncthreads();
    __threadfence();
    grid.sync();

    const float4* xg4 = (const float4*)xg;

    for (int iter = 0; iter < NITERS; ++iter) {
        for (int blk = 0; blk < NB; ++blk) {
            // =============== Phase A: r = y - x @ H_blk^T  (8 dots per WG) ===============
            // Register-cache x[b, :]: lane holds d = 2*lane + 128*j (pairs), j=0..7
            float4 xv4[8];
            #pragma unroll
            for (int j = 0; j < 8; ++j)
                xv4[j] = xg4[b * 512 + lane + 64 * j];

            #pragma unroll
            for (int rep = 0; rep < 2; ++rep) {
                int w = w0 + wave + rep * 4;
                size_t row = (size_t)blk * 64 + w;
                const float2* hre2 = (const float2*)(H_re + row * DIMD);
                const float2* him2 = (const float2*)(H_im + row * DIMD);
                float sr = 0.0f, si = 0.0f;
                #pragma unroll
                for (int j = 0; j < 8; ++j) {
                    float2 hr = hre2[lane + 64 * j];
                    float2 hi = him2[lane + 64 * j];
                    float4 xv = xv4[j];
                    // element 2*lane+128j   : (xv.x + i xv.y)
                    sr += xv.x * hr.x - xv.y * hi.x;
                    si += xv.x * hi.x + xv.y * hr.x;
                    // element 2*lane+128j+1 : (xv.z + i xv.w)
                    sr += xv.z * hr.y - xv.w * hi.y;
                    si += xv.z * hi.y + xv.w * hr.y;
                }
                #pragma unroll
                for (int off = 32; off >= 1; off >>= 1) {
                    sr += __shfl_xor(sr, off);
                    si += __shfl_xor(si, off);
                }
                if (lane == 0) {
                    int n = blk * 64 + w;
                    float yr, yi;
                    if (n < NH) { yr = y_re[b * NH + n]; yi = y_im[b * NH + n]; }
                    else        { int nn = n - NH; yr = y_re[b * NH + nn]; yi = -y_im[b * NH + nn]; }
                    rg[b * 64 + w] = make_float2(yr - sr, yi - si);
                }
            }
            __threadfence();
            grid.sync();

            // =============== Phase B: a2, std(global,ddof=1), sigma2(b), MLP, resid ======
            for (int idx = t; idx < 512; idx += NT) {
                float2 rv = rg[idx];
                rl[idx] = rv;
                a2s[idx] = rv.x * rv.x + rv.y * rv.y;
            }
            __syncthreads();
            // mean over all 512
            red[t] = a2s[t] + a2s[t + 256];
            __syncthreads();
            for (int off = 128; off > 0; off >>= 1) { if (t < off) red[t] += red[t + off]; __syncthreads(); }
            float meanv = red[0] * (1.0f / 512.0f);
            __syncthreads();
            // unbiased variance
            {
                float d0 = a2s[t] - meanv, d1 = a2s[t + 256] - meanv;
                red[t] = d0 * d0 + d1 * d1;
            }
            __syncthreads();
            for (int off = 128; off > 0; off >>= 1) { if (t < off) red[t] += red[t + off]; __syncthreads(); }
            float stdv = sqrtf(red[0] * (1.0f / 511.0f));
            __syncthreads();
            // sigma2 for this WG's b
            red[t] = (t < 64) ? a2s[b * 64 + t] : 0.0f;
            __syncthreads();
            for (int off = 128; off > 0; off >>= 1) { if (t < off) red[t] += red[t + off]; __syncthreads(); }
            float sigma2 = red[0] * (1.0f / 64.0f);
            __syncthreads();

            if (t < 64) {
                xts[t] = a2s[b * 64 + t] / stdv;
                taurow[t] = taug[blk * 512 + b * 64 + t];
            }
            __syncthreads();
            if (t < 64) {
                float acc = be[t];
                #pragma unroll
                for (int k = 0; k < 64; ++k) acc += wTe[k * 64 + t] * xts[k];
                hts[t] = 1.0f / (1.0f + expf(-acc));
            }
            __syncthreads();
            if (t < 64) {
                float acc = bu[t] + bm[t];
                #pragma unroll
                for (int k = 0; k < 64; ++k)
                    acc += wTu[k * 64 + t] * hts[k] + wTm[k * 64 + t] * taurow[k];
                float tn = fmaxf(acc, 0.0f);
                if (chunk == 0) taug[blk * 512 + b * 64 + t] = tn;
                float2 rv = rl[b * 64 + t];
                float sc = tn / sigma2;
                resid[t] = make_float2(rv.x * sc, rv.y * sc);
            }
            __syncthreads();

            // =============== Phase C: x[b, chunk] += resid @ conj(H_blk) / 65536 =========
            {
                int half = t >> 7, dloc = t & 127;
                int d = chunk * 128 + dloc;
                float ar = 0.0f, ai = 0.0f;
                #pragma unroll 8
                for (int k = 0; k < 32; ++k) {
                    int w = half * 32 + k;
                    size_t row = (size_t)blk * 64 + w;
                    float hr = H_re[row * DIMD + d];
                    float hi = H_im[row * DIMD + d];
                    float2 rs = resid[w];
                    // rs * conj(h)
                    ar += rs.x * hr + rs.y * hi;
                    ai += rs.y * hr - rs.x * hi;
                }
                if (half) cpart[dloc] = make_float2(ar, ai);
                __syncthreads();
                if (!half) {
                    float2 c = cpart[dloc];
                    float2 xv = xg[b * 1024 + d];
                    xv.x += (ar + c.x) * (1.0f / 65536.0f);
                    xv.y += (ai + c.y) * (1.0f / 65536.0f);
                    xg[b * 1024 + d] = xv;
                }
            }
            __threadfence();
            grid.sync();
        } // blk

        // =============== soft threshold: x = sgn(x)*relu(|x| - 1e-3*max|x|) ==============
        // T1: per-WG max over owned chunk
        {
            float lm = 0.0f;
            if (t < 128) {
                float2 xv = xg[b * 1024 + chunk * 128 + t];
                lm = sqrtf(xv.x * xv.x + xv.y * xv.y);
            }
            red[t] = lm;
            __syncthreads();
            for (int off = 128; off > 0; off >>= 1) { if (t < off) red[t] = fmaxf(red[t], red[t + off]); __syncthreads(); }
            if (t == 0) pm[g] = red[0];
        }
        __threadfence();
        grid.sync();
        // T2: global max, scale own chunk
        {
            red[t] = (t < 64) ? pm[t] : 0.0f;
            __syncthreads();
            for (int off = 128; off > 0; off >>= 1) { if (t < off) red[t] = fmaxf(red[t], red[t + off]); __syncthreads(); }
            float m = red[0];
            if (t < 128) {
                int d = chunk * 128 + t;
                float2 xv = xg[b * 1024 + d];
                float ax = sqrtf(xv.x * xv.x + xv.y * xv.y);
                float s = (ax > 0.0f) ? fmaxf(ax - 1e-3f * m, 0.0f) / ax : 0.0f;
                xv.x *= s; xv.y *= s;
                xg[b * 1024 + d] = xv;
            }
        }
        __threadfence();
        grid.sync();
    } // iter

    // =============== output ===============
    // out[0 .. 8191] = real(x)  (b*1024 + d)
    if (t < 128) {
        int d = chunk * 128 + t;
        out[b * 1024 + d] = xg[b * 1024 + d].x;
    }
    // out[8192 ..] = tau transposed: out[b][i][w] = tau[i][b][w]
    for (int i = g * 8; i < g * 8 + 8; ++i) {
        for (int idx = t; idx < 512; idx += NT) {
            int bb = idx >> 6, w = idx & 63;
            out[8192 + bb * (NB * BW) + i * 64 + w] = taug[i * 512 + idx];
        }
    }
}

extern "C" void kernel_launch(void* const* d_in, const int* in_sizes, int n_in,
                              void* d_out, int out_size, void* d_ws, size_t ws_size,
                              hipStream_t stream) {
    const float* y_re     = (const float*)d_in[0];
    const float* y_im     = (const float*)d_in[1];
    const float* H_re     = (const float*)d_in[2];
    const float* H_im     = (const float*)d_in[3];
    const float* estep_w  = (const float*)d_in[4];
    const float* estep_b  = (const float*)d_in[5];
    const float* update_w = (const float*)d_in[6];
    const float* update_b = (const float*)d_in[7];
    const float* memory_w = (const float*)d_in[8];
    const float* memory_b = (const float*)d_in[9];
    float* outp = (float*)d_out;
    float* wsp  = (float*)d_ws;

    void* args[] = {
        (void*)&y_re, (void*)&y_im, (void*)&H_re, (void*)&H_im,
        (void*)&estep_w, (void*)&estep_b, (void*)&update_w, (void*)&update_b,
        (void*)&memory_w, (void*)&memory_b, (void*)&outp, (void*)&wsp
    };
    hipLaunchCooperativeKernel((void*)robii_kernel, dim3(NWG), dim3(NT), args, 0, stream);
}

// Round 3
// 110654.248 us; speedup vs baseline: 1.7087x; 1.7087x over previous
//
#include <hip/hip_runtime.h>
#include <hip/hip_cooperative_groups.h>
#include <math.h>

namespace cg = cooperative_groups;

#define NT  256
#define NWG 64

__device__ __forceinline__ float wsum64(float v) {
    #pragma unroll
    for (int m = 1; m < 64; m <<= 1) v += __shfl_xor(v, m);
    return v;
}
__device__ __forceinline__ float wmax64(float v) {
    #pragma unroll
    for (int m = 1; m < 64; m <<= 1) v = fmaxf(v, __shfl_xor(v, m));
    return v;
}

// ws layout (floats):
//   partws: [2 parity][512 (b,w)][8 c] float2  -> 16384 floats @ 0
//   tauws:  [512 blk][8 b][64 w]               -> 262144 floats @ 16384
//   pmws:   [64]                               -> @ 278528
// total 278592 floats = 1,114,368 B  (<= round-1's proven 1,118,464 B)

__launch_bounds__(NT, 1)
__global__ void robii_kernel(
    const float* __restrict__ y_re, const float* __restrict__ y_im,
    const float* __restrict__ H_re, const float* __restrict__ H_im,
    const float* __restrict__ estep_w, const float* __restrict__ estep_b,
    const float* __restrict__ update_w, const float* __restrict__ update_b,
    const float* __restrict__ memory_w, const float* __restrict__ memory_b,
    float* __restrict__ out, float* __restrict__ ws)
{
    cg::grid_group grid = cg::this_grid();

    __shared__ float wTe[4096], wTu[4096], wTm[4096];  // transposed: wT[k*64+j] = w[j][k]
    __shared__ float be[64], bu[64], bm[64];
    __shared__ float a2s[512];
    __shared__ float redl[8];
    __shared__ float gmax[1];
    __shared__ float2 rown[64];
    __shared__ float xts[64], hts[64], taurow[64];
    __shared__ float2 resid[64];
    __shared__ float2 cpartC[4][32][4];
    __shared__ float2 x_l[128];     // this WG's x[b, c*128 .. c*128+127]

    const int g = blockIdx.x, t = threadIdx.x;
    const int c = g & 7;        // d-chunk; same-c WGs land on same XCD (g%8 round-robin)
    const int b = g >> 3;       // batch owned
    const int lane = t & 63, wv = t >> 6;
    const int sub = t & 31;     // column slice (4 floats)
    const int rbase = t >> 5;   // row group 0..7 (rows rbase+8j)

    float2* partws = (float2*)ws;            // [2][4096] float2
    float*  tauws  = ws + 16384;             // [512][8][64]
    float*  pmws   = ws + 278528;            // [64]

    // ---------------- init ----------------
    for (int i = t; i < 4096; i += NT) {
        int j = i >> 6, k = i & 63;
        wTe[k * 64 + j] = estep_w[i];
        wTu[k * 64 + j] = update_w[i];
        wTm[k * 64 + j] = memory_w[i];
    }
    if (t < 64) { be[t] = estep_b[t]; bu[t] = update_b[t]; bm[t] = memory_b[t]; taurow[t] = 1.0f; }
    if (t < 128) x_l[t] = make_float2(0.0f, 0.0f);
    for (int i = t; i < 4096; i += NT) tauws[g * 4096 + i] = 1.0f;
    __threadfence();
    grid.sync();

    const size_t hcol = (size_t)c * 128 + (size_t)sub * 4;

    #pragma unroll 1
    for (int iter = 0; iter < 10; ++iter) {
        #pragma unroll 1
        for (int blk = 0; blk < 512; ++blk) {
            const int par = blk & 1;
            __syncthreads();   // x_l / LDS reuse boundary

            // ---- load H tile into registers: rows rbase+8j, cols sub*4..+3 (re+im) ----
            float4 hre[8], him[8];
            {
                const float* pr = H_re + ((size_t)blk * 64 + rbase) * 1024 + hcol;
                const float* pi = H_im + ((size_t)blk * 64 + rbase) * 1024 + hcol;
                #pragma unroll
                for (int j = 0; j < 8; ++j) {
                    hre[j] = *(const float4*)(pr + (size_t)j * 8192);
                    him[j] = *(const float4*)(pi + (size_t)j * 8192);
                }
            }

            // ---- Phase A: partial z[b,w] over own 128-d chunk ----
            float2 xr0 = x_l[sub * 4 + 0], xr1 = x_l[sub * 4 + 1];
            float2 xr2 = x_l[sub * 4 + 2], xr3 = x_l[sub * 4 + 3];
            #pragma unroll
            for (int j = 0; j < 8; ++j) {
                float4 hr = hre[j], hi = him[j];
                float sr, si;
                sr  = xr0.x * hr.x - xr0.y * hi.x;  si  = xr0.x * hi.x + xr0.y * hr.x;
                sr += xr1.x * hr.y - xr1.y * hi.y;  si += xr1.x * hi.y + xr1.y * hr.y;
                sr += xr2.x * hr.z - xr2.y * hi.z;  si += xr2.x * hi.z + xr2.y * hr.z;
                sr += xr3.x * hr.w - xr3.y * hi.w;  si += xr3.x * hi.w + xr3.y * hr.w;
                #pragma unroll
                for (int m = 1; m < 32; m <<= 1) {
                    sr += __shfl_xor(sr, m); si += __shfl_xor(si, m);
                }
                if (sub == 0)
                    partws[par * 4096 + (b * 64 + rbase + 8 * j) * 8 + c] = make_float2(sr, si);
            }
            __threadfence();
            grid.sync();                       // THE one barrier per step

            // ---- tau prefetch for next block (prev-iter value; race-free by epoch) ----
            float tau_nxt = 0.0f;
            if (t < 64) tau_nxt = tauws[(((blk + 1) & 511) * 8 + b) * 64 + t];

            // ---- Phase B: reduce partials, r, a2, global std, sigma2(b), MLP, resid ----
            #pragma unroll
            for (int e = 0; e < 2; ++e) {
                int idx = t + e * 256;
                int b1 = idx >> 6, w = idx & 63;
                const float4* pp = (const float4*)(partws + (size_t)par * 4096 + (size_t)idx * 8);
                float4 v0 = pp[0], v1 = pp[1], v2 = pp[2], v3 = pp[3];
                float zr = v0.x + v0.z + v1.x + v1.z + v2.x + v2.z + v3.x + v3.z;
                float zi = v0.y + v0.w + v1.y + v1.w + v2.y + v2.w + v3.y + v3.w;
                int n = blk * 64 + w;
                float yr, yi;
                if (n < 16384) { yr = y_re[b1 * 16384 + n];         yi = y_im[b1 * 16384 + n]; }
                else           { yr = y_re[b1 * 16384 + n - 16384]; yi = -y_im[b1 * 16384 + n - 16384]; }
                float rr = yr - zr, ri = yi - zi;
                a2s[idx] = rr * rr + ri * ri;
                if (b1 == b) rown[w] = make_float2(rr, ri);
            }
            __syncthreads();

            float va = a2s[t] + a2s[t + 256];
            float s_ = wsum64(va);
            if (lane == 0) redl[wv] = s_;
            __syncthreads();
            float mean = (redl[0] + redl[1] + redl[2] + redl[3]) * (1.0f / 512.0f);
            float d0 = a2s[t] - mean, d1 = a2s[t + 256] - mean;
            float s2_ = wsum64(d0 * d0 + d1 * d1);
            float sg  = wsum64(a2s[b * 64 + lane]) * (1.0f / 64.0f);
            if (lane == 0) redl[4 + wv] = s2_;
            __syncthreads();
            float stdv = sqrtf((redl[4] + redl[5] + redl[6] + redl[7]) * (1.0f / 511.0f));
            if (t < 64) xts[t] = a2s[b * 64 + t] / stdv;
            __syncthreads();

            if (t < 64) {
                float acc = be[t];
                #pragma unroll
                for (int k = 0; k < 64; ++k) acc += wTe[k * 64 + t] * xts[k];
                hts[t] = 1.0f / (1.0f + expf(-acc));
            }
            __syncthreads();
            if (t < 64) {
                float acc = bu[t] + bm[t];
                #pragma unroll
                for (int k = 0; k < 64; ++k)
                    acc += wTu[k * 64 + t] * hts[k] + wTm[k * 64 + t] * taurow[k];
                float tn = fmaxf(acc, 0.0f);
                if (c == 0) tauws[(blk * 8 + b) * 64 + t] = tn;
                float2 rv = rown[t];
                float scl = tn / sg;
                resid[t] = make_float2(rv.x * scl, rv.y * scl);
            }
            __syncthreads();

            // ---- Phase C: x[b, own chunk] += resid @ conj(H) / 65536 (H from regs) ----
            float2 ac0 = make_float2(0.f, 0.f), ac1 = make_float2(0.f, 0.f);
            float2 ac2 = make_float2(0.f, 0.f), ac3 = make_float2(0.f, 0.f);
            #pragma unroll
            for (int j = 0; j < 8; ++j) {
                float2 rs = resid[rbase + 8 * j];
                float4 hr = hre[j], hi = him[j];
                ac0.x += rs.x * hr.x + rs.y * hi.x;  ac0.y += rs.y * hr.x - rs.x * hi.x;
                ac1.x += rs.x * hr.y + rs.y * hi.y;  ac1.y += rs.y * hr.y - rs.x * hi.y;
                ac2.x += rs.x * hr.z + rs.y * hi.z;  ac2.y += rs.y * hr.z - rs.x * hi.z;
                ac3.x += rs.x * hr.w + rs.y * hi.w;  ac3.y += rs.y * hr.w - rs.x * hi.w;
            }
            ac0.x += __shfl_xor(ac0.x, 32); ac0.y += __shfl_xor(ac0.y, 32);
            ac1.x += __shfl_xor(ac1.x, 32); ac1.y += __shfl_xor(ac1.y, 32);
            ac2.x += __shfl_xor(ac2.x, 32); ac2.y += __shfl_xor(ac2.y, 32);
            ac3.x += __shfl_xor(ac3.x, 32); ac3.y += __shfl_xor(ac3.y, 32);
            if ((t & 32) == 0) {
                cpartC[wv][sub][0] = ac0; cpartC[wv][sub][1] = ac1;
                cpartC[wv][sub][2] = ac2; cpartC[wv][sub][3] = ac3;
            }
            if (t < 64) taurow[t] = tau_nxt;       // commit prefetched tau
            __syncthreads();
            if (t < 128) {
                int sl = t >> 2, kk = t & 3;
                float2 s0 = cpartC[0][sl][kk], s1 = cpartC[1][sl][kk];
                float2 s2 = cpartC[2][sl][kk], s3 = cpartC[3][sl][kk];
                float2 xv = x_l[t];
                xv.x += (s0.x + s1.x + s2.x + s3.x) * (1.0f / 65536.0f);
                xv.y += (s0.y + s1.y + s2.y + s3.y) * (1.0f / 65536.0f);
                x_l[t] = xv;
            }
        } // blk

        // ---- soft threshold: x = sgn(x) * relu(|x| - 1e-3 * max|x| (global)) ----
        float lm = 0.0f;
        if (t < 128) { float2 xv = x_l[t]; lm = sqrtf(xv.x * xv.x + xv.y * xv.y); }
        lm = wmax64(lm);
        if (lane == 0) redl[wv] = lm;
        __syncthreads();
        if (t == 0) pmws[g] = fmaxf(fmaxf(redl[0], redl[1]), fmaxf(redl[2], redl[3]));
        __threadfence();
        grid.sync();
        float pv = (t < 64) ? pmws[t] : 0.0f;
        pv = wmax64(pv);
        if (t == 0) gmax[0] = pv;
        __syncthreads();
        float m = gmax[0];
        if (t < 128) {
            float2 xv = x_l[t];
            float ax = sqrtf(xv.x * xv.x + xv.y * xv.y);
            float s = (ax > 0.0f) ? fmaxf(ax - 1e-3f * m, 0.0f) / ax : 0.0f;
            x_l[t] = make_float2(xv.x * s, xv.y * s);
        }
        __syncthreads();
    } // iter

    // ---------------- output ----------------
    if (t < 128) out[b * 1024 + c * 128 + t] = x_l[t].x;
    for (int i = g * 8; i < g * 8 + 8; ++i) {
        for (int idx = t; idx < 512; idx += NT) {
            int bb = idx >> 6, w = idx & 63;
            out[8192 + bb * 32768 + i * 64 + w] = tauws[(i * 8 + bb) * 64 + w];
        }
    }
}

extern "C" void kernel_launch(void* const* d_in, const int* in_sizes, int n_in,
                              void* d_out, int out_size, void* d_ws, size_t ws_size,
                              hipStream_t stream) {
    (void)in_sizes; (void)n_in; (void)out_size; (void)ws_size;
    const float* y_re     = (const float*)d_in[0];
    const float* y_im     = (const float*)d_in[1];
    const float* H_re     = (const float*)d_in[2];
    const float* H_im     = (const float*)d_in[3];
    const float* estep_w  = (const float*)d_in[4];
    const float* estep_b  = (const float*)d_in[5];
    const float* update_w = (const float*)d_in[6];
    const float* update_b = (const float*)d_in[7];
    const float* memory_w = (const float*)d_in[8];
    const float* memory_b = (const float*)d_in[9];
    float* outp = (float*)d_out;
    float* wsp  = (float*)d_ws;

    void* args[] = {
        (void*)&y_re, (void*)&y_im, (void*)&H_re, (void*)&H_im,
        (void*)&estep_w, (void*)&estep_b, (void*)&update_w, (void*)&update_b,
        (void*)&memory_w, (void*)&memory_b, (void*)&outp, (void*)&wsp
    };
    hipLaunchCooperativeKernel((void*)robii_kernel, dim3(NWG), dim3(NT), args, 0, stream);
}

// Round 4
// 49815.466 us; speedup vs baseline: 3.7954x; 2.2213x over previous
//
#include <hip/hip_runtime.h>
#include <hip/hip_cooperative_groups.h>
#include <math.h>

namespace cg = cooperative_groups;

#define NT  256
#define NWG 64
#define SCOPE_AG __HIP_MEMORY_SCOPE_AGENT

// ---------- agent-scope cache-bypassing (sc0/sc1) data helpers ----------
__device__ __forceinline__ float ld_f(const float* p) {
    return __hip_atomic_load(p, __ATOMIC_RELAXED, SCOPE_AG);
}
__device__ __forceinline__ void st_f(float* p, float v) {
    __hip_atomic_store(p, v, __ATOMIC_RELAXED, SCOPE_AG);
}
__device__ __forceinline__ float2 ld_f2(const float2* p) {
    unsigned long long u = __hip_atomic_load((const unsigned long long*)p, __ATOMIC_RELAXED, SCOPE_AG);
    float2 r;
    r.x = __uint_as_float((unsigned)u);
    r.y = __uint_as_float((unsigned)(u >> 32));
    return r;
}
__device__ __forceinline__ void st_f2(float2* p, float2 v) {
    unsigned long long u = ((unsigned long long)__float_as_uint(v.y) << 32) | (unsigned long long)__float_as_uint(v.x);
    __hip_atomic_store((unsigned long long*)p, u, __ATOMIC_RELAXED, SCOPE_AG);
}

__device__ __forceinline__ float wsum64(float v) {
    #pragma unroll
    for (int m = 1; m < 64; m <<= 1) v += __shfl_xor(v, m);
    return v;
}
__device__ __forceinline__ float wmax64(float v) {
    #pragma unroll
    for (int m = 1; m < 64; m <<= 1) v = fmaxf(v, __shfl_xor(v, m));
    return v;
}

// Monotonic-count grid barrier. All cross-WG data moves via sc-atomics, so no
// cache writeback/invalidate is needed here. __syncthreads() before arrive
// drains this WG's outstanding vmem (stores reached the coherence point).
__device__ __forceinline__ void gbar(unsigned target, unsigned* cnt, int t) {
    __syncthreads();
    if (t == 0) {
        atomicAdd(cnt, 1u);                       // device-scope RMW (coherent)
        while (__hip_atomic_load(cnt, __ATOMIC_RELAXED, SCOPE_AG) < target)
            __builtin_amdgcn_s_sleep(1);
    }
    __syncthreads();
}

// ws layout (floats):
//   partws: [2 parity][512 (b,w)][8 c] float2  -> 16384 floats @ 0
//   tauws:  [512 blk][8 b][64 w]               -> 262144 floats @ 16384
//   pmws:   [64]                               -> @ 278528
//   cnt:    unsigned                           -> @ 278592
// total 1,114,372 B

__launch_bounds__(NT, 1)
__global__ void robii_kernel(
    const float* __restrict__ y_re, const float* __restrict__ y_im,
    const float* __restrict__ H_re, const float* __restrict__ H_im,
    const float* __restrict__ estep_w, const float* __restrict__ estep_b,
    const float* __restrict__ update_w, const float* __restrict__ update_b,
    const float* __restrict__ memory_w, const float* __restrict__ memory_b,
    float* __restrict__ out, float* __restrict__ ws)
{
    cg::grid_group grid = cg::this_grid();

    __shared__ float wTe[4096], wTu[4096], wTm[4096];  // transposed: wT[k*64+j] = w[j][k]
    __shared__ float be[64], bu[64], bm[64];
    __shared__ float a2s[512];
    __shared__ float redl[8];
    __shared__ float gmax[1];
    __shared__ float2 rown[64];
    __shared__ float xts[64], hts[64], taurow[64];
    __shared__ float2 resid[64];
    __shared__ float2 cpartC[4][32][4];
    __shared__ float2 x_l[128];     // this WG's x[b, c*128 .. c*128+127]

    const int g = blockIdx.x, t = threadIdx.x;
    const int c = g & 7;        // d-chunk owned
    const int b = g >> 3;       // batch owned
    const int lane = t & 63, wv = t >> 6;
    const int sub = t & 31;     // column slice (4 floats)
    const int rbase = t >> 5;   // row group 0..7 (rows rbase+8j)

    float2*   partws = (float2*)ws;            // [2][4096] float2
    float*    tauws  = ws + 16384;             // [512][8][64]
    float*    pmws   = ws + 278528;            // [64]
    unsigned* cnt    = (unsigned*)(ws + 278592);

    // ---------------- init ----------------
    for (int i = t; i < 4096; i += NT) {
        int j = i >> 6, k = i & 63;
        wTe[k * 64 + j] = estep_w[i];
        wTu[k * 64 + j] = update_w[i];
        wTm[k * 64 + j] = memory_w[i];
    }
    if (t < 64) { be[t] = estep_b[t]; bu[t] = update_b[t]; bm[t] = memory_b[t]; taurow[t] = 1.0f; }
    if (t < 128) x_l[t] = make_float2(0.0f, 0.0f);
    for (int i = t; i < 4096; i += NT) st_f(&tauws[g * 4096 + i], 1.0f);
    if (g == 0 && t == 0) *cnt = 0u;           // reset barrier counter (replay-safe)
    __threadfence();
    grid.sync();                               // single cg sync publishes the reset

    const size_t hcol = (size_t)c * 128 + (size_t)sub * 4;
    unsigned ep = 0;

    #pragma unroll 1
    for (int iter = 0; iter < 10; ++iter) {
        #pragma unroll 1
        for (int blk = 0; blk < 512; ++blk) {
            const int par = blk & 1;
            __syncthreads();   // x_l / LDS reuse boundary

            // ---- load H tile into registers: rows rbase+8j, cols sub*4..+3 (re+im) ----
            float4 hre[8], him[8];
            {
                const float* pr = H_re + ((size_t)blk * 64 + rbase) * 1024 + hcol;
                const float* pi = H_im + ((size_t)blk * 64 + rbase) * 1024 + hcol;
                #pragma unroll
                for (int j = 0; j < 8; ++j) {
                    hre[j] = *(const float4*)(pr + (size_t)j * 8192);
                    him[j] = *(const float4*)(pi + (size_t)j * 8192);
                }
            }

            // ---- Phase A: partial z[b,w] over own 128-d chunk ----
            float2 xr0 = x_l[sub * 4 + 0], xr1 = x_l[sub * 4 + 1];
            float2 xr2 = x_l[sub * 4 + 2], xr3 = x_l[sub * 4 + 3];
            #pragma unroll
            for (int j = 0; j < 8; ++j) {
                float4 hr = hre[j], hi = him[j];
                float sr, si;
                sr  = xr0.x * hr.x - xr0.y * hi.x;  si  = xr0.x * hi.x + xr0.y * hr.x;
                sr += xr1.x * hr.y - xr1.y * hi.y;  si += xr1.x * hi.y + xr1.y * hr.y;
                sr += xr2.x * hr.z - xr2.y * hi.z;  si += xr2.x * hi.z + xr2.y * hr.z;
                sr += xr3.x * hr.w - xr3.y * hi.w;  si += xr3.x * hi.w + xr3.y * hr.w;
                #pragma unroll
                for (int m = 1; m < 32; m <<= 1) {
                    sr += __shfl_xor(sr, m); si += __shfl_xor(si, m);
                }
                if (sub == 0)
                    st_f2(&partws[par * 4096 + (b * 64 + rbase + 8 * j) * 8 + c],
                          make_float2(sr, si));
            }
            ++ep;
            gbar(ep * 64u, cnt, t);            // THE one barrier per step

            // ---- tau prefetch for next block (prev-iter value; race-free by epoch) ----
            float tau_nxt = 0.0f;
            if (t < 64) tau_nxt = ld_f(&tauws[(((blk + 1) & 511) * 8 + b) * 64 + t]);

            // ---- Phase B: reduce partials, r, a2, global std, sigma2(b), MLP, resid ----
            #pragma unroll
            for (int e = 0; e < 2; ++e) {
                int idx = t + e * 256;
                int b1 = idx >> 6, w = idx & 63;
                const float2* pp = partws + (size_t)par * 4096 + (size_t)idx * 8;
                float zr = 0.0f, zi = 0.0f;
                #pragma unroll
                for (int cc = 0; cc < 8; ++cc) {
                    float2 v = ld_f2(pp + cc);
                    zr += v.x; zi += v.y;
                }
                int n = blk * 64 + w;
                float yr, yi;
                if (n < 16384) { yr = y_re[b1 * 16384 + n];         yi = y_im[b1 * 16384 + n]; }
                else           { yr = y_re[b1 * 16384 + n - 16384]; yi = -y_im[b1 * 16384 + n - 16384]; }
                float rr = yr - zr, ri = yi - zi;
                a2s[idx] = rr * rr + ri * ri;
                if (b1 == b) rown[w] = make_float2(rr, ri);
            }
            __syncthreads();

            float va = a2s[t] + a2s[t + 256];
            float s_ = wsum64(va);
            if (lane == 0) redl[wv] = s_;
            __syncthreads();
            float mean = (redl[0] + redl[1] + redl[2] + redl[3]) * (1.0f / 512.0f);
            float d0 = a2s[t] - mean, d1 = a2s[t + 256] - mean;
            float s2_ = wsum64(d0 * d0 + d1 * d1);
            float sg  = wsum64(a2s[b * 64 + lane]) * (1.0f / 64.0f);
            if (lane == 0) redl[4 + wv] = s2_;
            __syncthreads();
            float stdv = sqrtf((redl[4] + redl[5] + redl[6] + redl[7]) * (1.0f / 511.0f));
            if (t < 64) xts[t] = a2s[b * 64 + t] / stdv;
            __syncthreads();

            if (t < 64) {
                float acc = be[t];
                #pragma unroll
                for (int k = 0; k < 64; ++k) acc += wTe[k * 64 + t] * xts[k];
                hts[t] = 1.0f / (1.0f + expf(-acc));
            }
            __syncthreads();
            if (t < 64) {
                float acc = bu[t] + bm[t];
                #pragma unroll
                for (int k = 0; k < 64; ++k)
                    acc += wTu[k * 64 + t] * hts[k] + wTm[k * 64 + t] * taurow[k];
                float tn = fmaxf(acc, 0.0f);
                if (c == 0) st_f(&tauws[(blk * 8 + b) * 64 + t], tn);
                float2 rv = rown[t];
                float scl = tn / sg;
                resid[t] = make_float2(rv.x * scl, rv.y * scl);
            }
            __syncthreads();

            // ---- Phase C: x[b, own chunk] += resid @ conj(H) / 65536 (H from regs) ----
            float2 ac0 = make_float2(0.f, 0.f), ac1 = make_float2(0.f, 0.f);
            float2 ac2 = make_float2(0.f, 0.f), ac3 = make_float2(0.f, 0.f);
            #pragma unroll
            for (int j = 0; j < 8; ++j) {
                float2 rs = resid[rbase + 8 * j];
                float4 hr = hre[j], hi = him[j];
                ac0.x += rs.x * hr.x + rs.y * hi.x;  ac0.y += rs.y * hr.x - rs.x * hi.x;
                ac1.x += rs.x * hr.y + rs.y * hi.y;  ac1.y += rs.y * hr.y - rs.x * hi.y;
                ac2.x += rs.x * hr.z + rs.y * hi.z;  ac2.y += rs.y * hr.z - rs.x * hi.z;
                ac3.x += rs.x * hr.w + rs.y * hi.w;  ac3.y += rs.y * hr.w - rs.x * hi.w;
            }
            ac0.x += __shfl_xor(ac0.x, 32); ac0.y += __shfl_xor(ac0.y, 32);
            ac1.x += __shfl_xor(ac1.x, 32); ac1.y += __shfl_xor(ac1.y, 32);
            ac2.x += __shfl_xor(ac2.x, 32); ac2.y += __shfl_xor(ac2.y, 32);
            ac3.x += __shfl_xor(ac3.x, 32); ac3.y += __shfl_xor(ac3.y, 32);
            if ((t & 32) == 0) {
                cpartC[wv][sub][0] = ac0; cpartC[wv][sub][1] = ac1;
                cpartC[wv][sub][2] = ac2; cpartC[wv][sub][3] = ac3;
            }
            if (t < 64) taurow[t] = tau_nxt;       // commit prefetched tau
            __syncthreads();
            if (t < 128) {
                int sl = t >> 2, kk = t & 3;
                float2 s0 = cpartC[0][sl][kk], s1 = cpartC[1][sl][kk];
                float2 s2 = cpartC[2][sl][kk], s3 = cpartC[3][sl][kk];
                float2 xv = x_l[t];
                xv.x += (s0.x + s1.x + s2.x + s3.x) * (1.0f / 65536.0f);
                xv.y += (s0.y + s1.y + s2.y + s3.y) * (1.0f / 65536.0f);
                x_l[t] = xv;
            }
        } // blk

        // ---- soft threshold: x = sgn(x) * relu(|x| - 1e-3 * max|x| (global)) ----
        float lm = 0.0f;
        if (t < 128) { float2 xv = x_l[t]; lm = sqrtf(xv.x * xv.x + xv.y * xv.y); }
        lm = wmax64(lm);
        if (lane == 0) redl[wv] = lm;
        __syncthreads();
        if (t == 0) st_f(&pmws[g], fmaxf(fmaxf(redl[0], redl[1]), fmaxf(redl[2], redl[3])));
        ++ep;
        gbar(ep * 64u, cnt, t);
        float pv = (t < 64) ? ld_f(&pmws[t]) : 0.0f;
        pv = wmax64(pv);
        if (t == 0) gmax[0] = pv;
        __syncthreads();
        float m = gmax[0];
        if (t < 128) {
            float2 xv = x_l[t];
            float ax = sqrtf(xv.x * xv.x + xv.y * xv.y);
            float s = (ax > 0.0f) ? fmaxf(ax - 1e-3f * m, 0.0f) / ax : 0.0f;
            x_l[t] = make_float2(xv.x * s, xv.y * s);
        }
        __syncthreads();
    } // iter

    // ---------------- output ----------------
    if (t < 128) out[b * 1024 + c * 128 + t] = x_l[t].x;
    for (int i = g * 8; i < g * 8 + 8; ++i) {
        for (int idx = t; idx < 512; idx += NT) {
            int bb = idx >> 6, w = idx & 63;
            out[8192 + bb * 32768 + i * 64 + w] = ld_f(&tauws[(i * 8 + bb) * 64 + w]);
        }
    }
}

extern "C" void kernel_launch(void* const* d_in, const int* in_sizes, int n_in,
                              void* d_out, int out_size, void* d_ws, size_t ws_size,
                              hipStream_t stream) {
    (void)in_sizes; (void)n_in; (void)out_size; (void)ws_size;
    const float* y_re     = (const float*)d_in[0];
    const float* y_im     = (const float*)d_in[1];
    const float* H_re     = (const float*)d_in[2];
    const float* H_im     = (const float*)d_in[3];
    const float* estep_w  = (const float*)d_in[4];
    const float* estep_b  = (const float*)d_in[5];
    const float* update_w = (const float*)d_in[6];
    const float* update_b = (const float*)d_in[7];
    const float* memory_w = (const float*)d_in[8];
    const float* memory_b = (const float*)d_in[9];
    float* outp = (float*)d_out;
    float* wsp  = (float*)d_ws;

    void* args[] = {
        (void*)&y_re, (void*)&y_im, (void*)&H_re, (void*)&H_im,
        (void*)&estep_w, (void*)&estep_b, (void*)&update_w, (void*)&update_b,
        (void*)&memory_w, (void*)&memory_b, (void*)&outp, (void*)&wsp
    };
    hipLaunchCooperativeKernel((void*)robii_kernel, dim3(NWG), dim3(NT), args, 0, stream);
}

// Round 5
// 42313.773 us; speedup vs baseline: 4.4683x; 1.1773x over previous
//
#include <hip/hip_runtime.h>
#include <hip/hip_cooperative_groups.h>
#include <math.h>

namespace cg = cooperative_groups;

#define NT  256
#define NWG 64
#define SCOPE_AG __HIP_MEMORY_SCOPE_AGENT

// ---------- agent-scope cache-bypassing (sc0/sc1) data helpers ----------
__device__ __forceinline__ float ld_f(const float* p) {
    return __hip_atomic_load(p, __ATOMIC_RELAXED, SCOPE_AG);
}
__device__ __forceinline__ void st_f(float* p, float v) {
    __hip_atomic_store(p, v, __ATOMIC_RELAXED, SCOPE_AG);
}
__device__ __forceinline__ unsigned ld_u(const unsigned* p) {
    return __hip_atomic_load(p, __ATOMIC_RELAXED, SCOPE_AG);
}
__device__ __forceinline__ void st_u(unsigned* p, unsigned v) {
    __hip_atomic_store(p, v, __ATOMIC_RELAXED, SCOPE_AG);
}
__device__ __forceinline__ float2 ld_f2(const float2* p) {
    unsigned long long u = __hip_atomic_load((const unsigned long long*)p, __ATOMIC_RELAXED, SCOPE_AG);
    float2 r;
    r.x = __uint_as_float((unsigned)u);
    r.y = __uint_as_float((unsigned)(u >> 32));
    return r;
}
__device__ __forceinline__ void st_f2(float2* p, float2 v) {
    unsigned long long u = ((unsigned long long)__float_as_uint(v.y) << 32) | (unsigned long long)__float_as_uint(v.x);
    __hip_atomic_store((unsigned long long*)p, u, __ATOMIC_RELAXED, SCOPE_AG);
}

__device__ __forceinline__ float wsum64(float v) {
    #pragma unroll
    for (int m = 1; m < 64; m <<= 1) v += __shfl_xor(v, m);
    return v;
}
__device__ __forceinline__ float wmax64(float v) {
    #pragma unroll
    for (int m = 1; m < 64; m <<= 1) v = fmaxf(v, __shfl_xor(v, m));
    return v;
}

// ws layout (floats) — total EXACTLY 279,616 floats = 1,118,464 B (proven-safe):
//   partws: [2 parity][512 (b,w)][8 c] float2  -> 16384 floats @ 0
//   tauws:  [512 blk][8 b][64 w]               -> 262144 floats @ 16384
//   pmws:   [64]                               -> @ 278528
//   flags:  unsigned[64 * 16] (64B stride)     -> @ 278592 .. 279616

__launch_bounds__(NT, 1)
__global__ void robii_kernel(
    const float* __restrict__ y_re, const float* __restrict__ y_im,
    const float* __restrict__ H_re, const float* __restrict__ H_im,
    const float* __restrict__ estep_w, const float* __restrict__ estep_b,
    const float* __restrict__ update_w, const float* __restrict__ update_b,
    const float* __restrict__ memory_w, const float* __restrict__ memory_b,
    float* __restrict__ out, float* __restrict__ ws)
{
    cg::grid_group grid = cg::this_grid();

    __shared__ float wTe[4096], wTu[4096], wTm[4096];  // transposed: wT[k*64+j] = w[j][k]
    __shared__ float be[64], bu[64], bm[64];
    __shared__ float a2s[512];
    __shared__ float redl[8];
    __shared__ float gmax[1];
    __shared__ float2 rown[64];
    __shared__ float xts[64], hts[64], taurow[64];
    __shared__ float2 resid[64];
    __shared__ float2 cpartC[4][32][4];
    __shared__ float2 x_l[128];     // this WG's x[b, c*128 .. c*128+127]

    const int g = blockIdx.x, t = threadIdx.x;
    const int c = g & 7;        // d-chunk owned; same-c WGs co-locate per XCD (g%8)
    const int b = g >> 3;       // batch owned
    const int lane = t & 63, wv = t >> 6;
    const int sub = t & 31;     // column slice (4 floats)
    const int rbase = t >> 5;   // row group 0..7 (rows rbase+8j)

    float2*   partws = (float2*)ws;            // [2][4096] float2
    float*    tauws  = ws + 16384;             // [512][8][64]
    float*    pmws   = ws + 278528;            // [64]
    unsigned* flags  = (unsigned*)(ws + 278592); // [64*16]

    // ---------------- init ----------------
    for (int i = t; i < 4096; i += NT) {
        int j = i >> 6, k = i & 63;
        wTe[k * 64 + j] = estep_w[i];
        wTu[k * 64 + j] = update_w[i];
        wTm[k * 64 + j] = memory_w[i];
    }
    if (t < 64) { be[t] = estep_b[t]; bu[t] = update_b[t]; bm[t] = memory_b[t]; taurow[t] = 1.0f; }
    if (t < 128) x_l[t] = make_float2(0.0f, 0.0f);
    for (int i = t; i < 4096; i += NT) st_f(&tauws[g * 4096 + i], 1.0f);
    if (t == 0) st_u(&flags[g * 16], 0u);      // each WG resets its OWN flag slot
    __threadfence();
    grid.sync();                               // single cg sync publishes the resets

    const size_t hcol = (size_t)c * 128 + (size_t)sub * 4;
    unsigned ep = 0;

    // H double-buffer register banks
    float4 hAre[8], hAim[8], hBre[8], hBim[8];

#define PREF(DRE, DIM_, BLKN) do {                                                   \
        const float* _pr = H_re + ((size_t)(BLKN) * 64 + rbase) * 1024 + hcol;       \
        const float* _pi = H_im + ((size_t)(BLKN) * 64 + rbase) * 1024 + hcol;       \
        _Pragma("unroll")                                                            \
        for (int _j = 0; _j < 8; ++_j) {                                             \
            DRE[_j]  = *(const float4*)(_pr + (size_t)_j * 8192);                    \
            DIM_[_j] = *(const float4*)(_pi + (size_t)_j * 8192);                    \
        }                                                                            \
    } while (0)

    PREF(hAre, hAim, 0);   // prologue: bank A <- block 0

#define STEP(BLK, CRE, CIM, NRE, NIM) do {                                           \
        const int blk = (BLK);                                                       \
        const int par = blk & 1;                                                     \
        __syncthreads();   /* x_l / LDS reuse boundary */                            \
        /* ---- Phase A: partial z[b,w] over own 128-d chunk (H from CUR bank) */    \
        float2 xr0 = x_l[sub * 4 + 0], xr1 = x_l[sub * 4 + 1];                       \
        float2 xr2 = x_l[sub * 4 + 2], xr3 = x_l[sub * 4 + 3];                       \
        _Pragma("unroll")                                                            \
        for (int j = 0; j < 8; ++j) {                                                \
            float4 hr = CRE[j], hi = CIM[j];                                         \
            float sr, si;                                                            \
            sr  = xr0.x * hr.x - xr0.y * hi.x;  si  = xr0.x * hi.x + xr0.y * hr.x;   \
            sr += xr1.x * hr.y - xr1.y * hi.y;  si += xr1.x * hi.y + xr1.y * hr.y;   \
            sr += xr2.x * hr.z - xr2.y * hi.z;  si += xr2.x * hi.z + xr2.y * hr.z;   \
            sr += xr3.x * hr.w - xr3.y * hi.w;  si += xr3.x * hi.w + xr3.y * hr.w;   \
            _Pragma("unroll")                                                        \
            for (int m = 1; m < 32; m <<= 1) {                                       \
                sr += __shfl_xor(sr, m); si += __shfl_xor(si, m);                    \
            }                                                                        \
            if (sub == 0)                                                            \
                st_f2(&partws[par * 4096 + (b * 64 + rbase + 8 * j) * 8 + c],        \
                      make_float2(sr, si));                                          \
        }                                                                            \
        ++ep;                                                                        \
        /* ---- barrier ARRIVE (stores drained by syncthreads) ---- */               \
        __syncthreads();                                                             \
        if (t == 0) st_u(&flags[g * 16], ep);                                        \
        /* ---- overlap zone: prefetch H(blk+1) + tau(blk+1) under the wait ---- */  \
        PREF(NRE, NIM, ((blk + 1) & 511));                                           \
        float tau_nxt = 0.0f;                                                        \
        if (t < 64) tau_nxt = ld_f(&tauws[(((blk + 1) & 511) * 8 + b) * 64 + t]);    \
        /* ---- barrier WAIT: every lane polls one WG slot ---- */                   \
        if (t < 64) {                                                                \
            while (ld_u(&flags[t * 16]) < ep) __builtin_amdgcn_s_sleep(1);           \
        }                                                                            \
        __syncthreads();                                                             \
        /* ---- Phase B: reduce partials, r, a2, std, sigma2(b), MLP, resid ---- */  \
        _Pragma("unroll")                                                            \
        for (int e = 0; e < 2; ++e) {                                                \
            int idx = t + e * 256;                                                   \
            int b1 = idx >> 6, w = idx & 63;                                         \
            const float2* pp = partws + (size_t)par * 4096 + (size_t)idx * 8;        \
            float zr = 0.0f, zi = 0.0f;                                              \
            _Pragma("unroll")                                                        \
            for (int cc = 0; cc < 8; ++cc) {                                         \
                float2 v = ld_f2(pp + cc);                                           \
                zr += v.x; zi += v.y;                                                \
            }                                                                        \
            int n = blk * 64 + w;                                                    \
            float yr, yi;                                                            \
            if (n < 16384) { yr = y_re[b1 * 16384 + n];         yi = y_im[b1 * 16384 + n]; } \
            else           { yr = y_re[b1 * 16384 + n - 16384]; yi = -y_im[b1 * 16384 + n - 16384]; } \
            float rr = yr - zr, ri = yi - zi;                                        \
            a2s[idx] = rr * rr + ri * ri;                                            \
            if (b1 == b) rown[w] = make_float2(rr, ri);                              \
        }                                                                            \
        __syncthreads();                                                             \
        float va = a2s[t] + a2s[t + 256];                                            \
        float s_ = wsum64(va);                                                       \
        if (lane == 0) redl[wv] = s_;                                                \
        __syncthreads();                                                             \
        float mean = (redl[0] + redl[1] + redl[2] + redl[3]) * (1.0f / 512.0f);      \
        float d0 = a2s[t] - mean, d1 = a2s[t + 256] - mean;                          \
        float s2_ = wsum64(d0 * d0 + d1 * d1);                                       \
        float sg  = wsum64(a2s[b * 64 + lane]) * (1.0f / 64.0f);                     \
        if (lane == 0) redl[4 + wv] = s2_;                                           \
        __syncthreads();                                                             \
        float stdv = sqrtf((redl[4] + redl[5] + redl[6] + redl[7]) * (1.0f / 511.0f)); \
        if (t < 64) xts[t] = a2s[b * 64 + t] / stdv;                                 \
        __syncthreads();                                                             \
        if (t < 64) {                                                                \
            float acc = be[t];                                                       \
            _Pragma("unroll")                                                        \
            for (int k = 0; k < 64; ++k) acc += wTe[k * 64 + t] * xts[k];            \
            hts[t] = 1.0f / (1.0f + expf(-acc));                                     \
        }                                                                            \
        __syncthreads();                                                             \
        if (t < 64) {                                                                \
            float acc = bu[t] + bm[t];                                               \
            _Pragma("unroll")                                                        \
            for (int k = 0; k < 64; ++k)                                             \
                acc += wTu[k * 64 + t] * hts[k] + wTm[k * 64 + t] * taurow[k];       \
            float tn = fmaxf(acc, 0.0f);                                             \
            if (c == 0) st_f(&tauws[(blk * 8 + b) * 64 + t], tn);                    \
            float2 rv = rown[t];                                                     \
            float scl = tn / sg;                                                     \
            resid[t] = make_float2(rv.x * scl, rv.y * scl);                          \
        }                                                                            \
        __syncthreads();                                                             \
        /* ---- Phase C: x[b, own chunk] += resid @ conj(H) / 65536 (CUR bank) */    \
        float2 ac0 = make_float2(0.f, 0.f), ac1 = make_float2(0.f, 0.f);             \
        float2 ac2 = make_float2(0.f, 0.f), ac3 = make_float2(0.f, 0.f);             \
        _Pragma("unroll")                                                            \
        for (int j = 0; j < 8; ++j) {                                                \
            float2 rs = resid[rbase + 8 * j];                                        \
            float4 hr = CRE[j], hi = CIM[j];                                         \
            ac0.x += rs.x * hr.x + rs.y * hi.x;  ac0.y += rs.y * hr.x - rs.x * hi.x; \
            ac1.x += rs.x * hr.y + rs.y * hi.y;  ac1.y += rs.y * hr.y - rs.x * hi.y; \
            ac2.x += rs.x * hr.z + rs.y * hi.z;  ac2.y += rs.y * hr.z - rs.x * hi.z; \
            ac3.x += rs.x * hr.w + rs.y * hi.w;  ac3.y += rs.y * hr.w - rs.x * hi.w; \
        }                                                                            \
        ac0.x += __shfl_xor(ac0.x, 32); ac0.y += __shfl_xor(ac0.y, 32);              \
        ac1.x += __shfl_xor(ac1.x, 32); ac1.y += __shfl_xor(ac1.y, 32);              \
        ac2.x += __shfl_xor(ac2.x, 32); ac2.y += __shfl_xor(ac2.y, 32);              \
        ac3.x += __shfl_xor(ac3.x, 32); ac3.y += __shfl_xor(ac3.y, 32);              \
        if ((t & 32) == 0) {                                                         \
            cpartC[wv][sub][0] = ac0; cpartC[wv][sub][1] = ac1;                      \
            cpartC[wv][sub][2] = ac2; cpartC[wv][sub][3] = ac3;                      \
        }                                                                            \
        if (t < 64) taurow[t] = tau_nxt;       /* commit prefetched tau */           \
        __syncthreads();                                                             \
        if (t < 128) {                                                               \
            int sl = t >> 2, kk = t & 3;                                             \
            float2 s0 = cpartC[0][sl][kk], s1 = cpartC[1][sl][kk];                   \
            float2 s2 = cpartC[2][sl][kk], s3 = cpartC[3][sl][kk];                   \
            float2 xv = x_l[t];                                                      \
            xv.x += (s0.x + s1.x + s2.x + s3.x) * (1.0f / 65536.0f);                 \
            xv.y += (s0.y + s1.y + s2.y + s3.y) * (1.0f / 65536.0f);                 \
            x_l[t] = xv;                                                             \
        }                                                                            \
    } while (0)

    #pragma unroll 1
    for (int iter = 0; iter < 10; ++iter) {
        #pragma unroll 1
        for (int blk2 = 0; blk2 < 512; blk2 += 2) {
            STEP(blk2,     hAre, hAim, hBre, hBim);
            STEP(blk2 + 1, hBre, hBim, hAre, hAim);
        }

        // ---- soft threshold: x = sgn(x) * relu(|x| - 1e-3 * max|x| (global)) ----
        float lm = 0.0f;
        if (t < 128) { float2 xv = x_l[t]; lm = sqrtf(xv.x * xv.x + xv.y * xv.y); }
        lm = wmax64(lm);
        if (lane == 0) redl[wv] = lm;
        __syncthreads();
        if (t == 0) st_f(&pmws[g], fmaxf(fmaxf(redl[0], redl[1]), fmaxf(redl[2], redl[3])));
        ++ep;
        __syncthreads();
        if (t == 0) st_u(&flags[g * 16], ep);
        if (t < 64) {
            while (ld_u(&flags[t * 16]) < ep) __builtin_amdgcn_s_sleep(1);
        }
        __syncthreads();
        float pv = (t < 64) ? ld_f(&pmws[t]) : 0.0f;
        pv = wmax64(pv);
        if (t == 0) gmax[0] = pv;
        __syncthreads();
        float m = gmax[0];
        if (t < 128) {
            float2 xv = x_l[t];
            float ax = sqrtf(xv.x * xv.x + xv.y * xv.y);
            float s = (ax > 0.0f) ? fmaxf(ax - 1e-3f * m, 0.0f) / ax : 0.0f;
            x_l[t] = make_float2(xv.x * s, xv.y * s);
        }
        __syncthreads();
    } // iter

    // ---------------- output ----------------
    if (t < 128) out[b * 1024 + c * 128 + t] = x_l[t].x;
    for (int i = g * 8; i < g * 8 + 8; ++i) {
        for (int idx = t; idx < 512; idx += NT) {
            int bb = idx >> 6, w = idx & 63;
            out[8192 + bb * 32768 + i * 64 + w] = ld_f(&tauws[(i * 8 + bb) * 64 + w]);
        }
    }
#undef STEP
#undef PREF
}

extern "C" void kernel_launch(void* const* d_in, const int* in_sizes, int n_in,
                              void* d_out, int out_size, void* d_ws, size_t ws_size,
                              hipStream_t stream) {
    (void)in_sizes; (void)n_in; (void)out_size; (void)ws_size;
    const float* y_re     = (const float*)d_in[0];
    const float* y_im     = (const float*)d_in[1];
    const float* H_re     = (const float*)d_in[2];
    const float* H_im     = (const float*)d_in[3];
    const float* estep_w  = (const float*)d_in[4];
    const float* estep_b  = (const float*)d_in[5];
    const float* update_w = (const float*)d_in[6];
    const float* update_b = (const float*)d_in[7];
    const float* memory_w = (const float*)d_in[8];
    const float* memory_b = (const float*)d_in[9];
    float* outp = (float*)d_out;
    float* wsp  = (float*)d_ws;

    void* args[] = {
        (void*)&y_re, (void*)&y_im, (void*)&H_re, (void*)&H_im,
        (void*)&estep_w, (void*)&estep_b, (void*)&update_w, (void*)&update_b,
        (void*)&memory_w, (void*)&memory_b, (void*)&outp, (void*)&wsp
    };
    hipLaunchCooperativeKernel((void*)robii_kernel, dim3(NWG), dim3(NT), args, 0, stream);
}

// Round 10
// 39184.363 us; speedup vs baseline: 4.8252x; 1.0799x over previous
//
#include <hip/hip_runtime.h>
#include <math.h>

#define NT  256
#define NWG 64
#define SCOPE_AG __HIP_MEMORY_SCOPE_AGENT

// ---------- agent-scope cache-bypassing data helpers ----------
__device__ __forceinline__ float ld_f(const float* p) {
    return __hip_atomic_load(p, __ATOMIC_RELAXED, SCOPE_AG);
}
__device__ __forceinline__ void st_f(float* p, float v) {
    __hip_atomic_store(p, v, __ATOMIC_RELAXED, SCOPE_AG);
}
__device__ __forceinline__ unsigned ld_u(const unsigned* p) {
    return __hip_atomic_load(p, __ATOMIC_RELAXED, SCOPE_AG);
}
__device__ __forceinline__ void st_u(unsigned* p, unsigned v) {
    __hip_atomic_store(p, v, __ATOMIC_RELAXED, SCOPE_AG);
}
__device__ __forceinline__ float2 ld_f2(const float2* p) {
    unsigned long long u = __hip_atomic_load((const unsigned long long*)p, __ATOMIC_RELAXED, SCOPE_AG);
    float2 r;
    r.x = __uint_as_float((unsigned)u);
    r.y = __uint_as_float((unsigned)(u >> 32));
    return r;
}
__device__ __forceinline__ void st_f2(float2* p, float2 v) {
    unsigned long long u = ((unsigned long long)__float_as_uint(v.y) << 32) | (unsigned long long)__float_as_uint(v.x);
    __hip_atomic_store((unsigned long long*)p, u, __ATOMIC_RELAXED, SCOPE_AG);
}

__device__ __forceinline__ float wsum64(float v) {
    #pragma unroll
    for (int m = 1; m < 64; m <<= 1) v += __shfl_xor(v, m);
    return v;
}
__device__ __forceinline__ float wmax64(float v) {
    #pragma unroll
    for (int m = 1; m < 64; m <<= 1) v = fmaxf(v, __shfl_xor(v, m));
    return v;
}

// ws layout (floats) — total EXACTLY 279,616 floats = 1,118,464 B (proven-safe):
//   partws: [2 parity][512 (b,w)][8 c] float2  -> 16384 floats @ 0
//   tauws:  [512 blk][8 b][64 w]               -> 262144 floats @ 16384
//   pmws:   [64]                               -> @ 278528
//   flags:  unsigned[2 plane][64 wg][8 stride] -> @ 278592 .. 279616
//
// Barrier protocol (replay-safe, reset-free): ping-pong planes by ep parity,
// EQUALITY polling. Stale values (previous replay / 0xAA poison / garbage)
// never compare equal to the current epoch, so no early passage; bounded
// barrier lead (max 1) guarantees a plane is never overwritten while polled.

__launch_bounds__(NT, 1)
__global__ void robii_kernel(
    const float* __restrict__ y_re, const float* __restrict__ y_im,
    const float* __restrict__ H_re, const float* __restrict__ H_im,
    const float* __restrict__ estep_w, const float* __restrict__ estep_b,
    const float* __restrict__ update_w, const float* __restrict__ update_b,
    const float* __restrict__ memory_w, const float* __restrict__ memory_b,
    float* __restrict__ out, float* __restrict__ ws)
{
    __shared__ float wTe[4096], wTu[4096], wTm[4096];  // transposed: wT[k*64+j] = w[j][k]
    __shared__ float be[64], bu[64], bm[64];
    __shared__ float a2s[512];
    __shared__ float redl[8];
    __shared__ float gmax[1];
    __shared__ float2 rown[64];
    __shared__ float xts[64], hts[64], taurow[64];
    __shared__ float2 resid[64];
    __shared__ float2 cpartC[4][32][4];   // Phase-C scratch; ALSO aliased as MLP partials
    __shared__ float2 x_l[128];     // this WG's x[b, c*128 .. c*128+127]

    float* mpartf = (float*)cpartC;  // [4][64] floats, aliased (time-shared with Phase C)

    const int g = blockIdx.x, t = threadIdx.x;
    const int c = g & 7;        // d-chunk owned
    const int b = g >> 3;       // batch owned
    const int lane = t & 63, wv = t >> 6;
    const int sub = t & 31;     // column slice (4 floats)
    const int rbase = t >> 5;   // row group 0..7 (rows rbase+8j)

    float2*   partws = (float2*)ws;            // [2][4096] float2
    float*    tauws  = ws + 16384;             // [512][8][64]
    float*    pmws   = ws + 278528;            // [64]
    unsigned* flags  = (unsigned*)(ws + 278592); // [2][64][8]

    // ---------------- init ----------------
    for (int i = t; i < 4096; i += NT) {
        int j = i >> 6, k = i & 63;
        wTe[k * 64 + j] = estep_w[i];
        wTu[k * 64 + j] = update_w[i];
        wTm[k * 64 + j] = memory_w[i];
    }
    if (t < 64) { be[t] = estep_b[t]; bu[t] = update_b[t]; bm[t] = memory_b[t]; taurow[t] = 1.0f; }
    if (t < 128) x_l[t] = make_float2(0.0f, 0.0f);
    for (int i = t; i < 4096; i += NT) st_f(&tauws[g * 4096 + i], 1.0f);

    unsigned ep = 1;
    // init barrier (ep=1, plane 1): publishes tau init. NO resets needed.
    {
        unsigned* plane = flags + ((ep & 1u) << 9);
        __syncthreads();                       // drains this WG's tau stores
        if (t == 0) st_u(&plane[g * 8], ep);
        if (t < 64) {
            while (ld_u(&plane[t * 8]) != ep) __builtin_amdgcn_s_sleep(1);
        }
        __syncthreads();
    }

    const size_t hcol = (size_t)c * 128 + (size_t)sub * 4;

    // H double-buffer register banks
    float4 hAre[8], hAim[8], hBre[8], hBim[8];

#define PREF(DRE, DIM_, BLKN) do {                                                   \
        const float* _pr = H_re + ((size_t)(BLKN) * 64 + rbase) * 1024 + hcol;       \
        const float* _pi = H_im + ((size_t)(BLKN) * 64 + rbase) * 1024 + hcol;       \
        _Pragma("unroll")                                                            \
        for (int _j = 0; _j < 8; ++_j) {                                             \
            DRE[_j]  = *(const float4*)(_pr + (size_t)_j * 8192);                    \
            DIM_[_j] = *(const float4*)(_pi + (size_t)_j * 8192);                    \
        }                                                                            \
    } while (0)

    PREF(hAre, hAim, 0);   // prologue: bank A <- block 0

#define STEP(BLK, CRE, CIM, NRE, NIM) do {                                           \
        const int blk = (BLK);                                                       \
        const int par = blk & 1;                                                     \
        __syncthreads();   /* x_l / LDS reuse boundary */                            \
        /* ---- Phase A: partial z[b,w] over own 128-d chunk (H from CUR bank) */    \
        float2 xr0 = x_l[sub * 4 + 0], xr1 = x_l[sub * 4 + 1];                       \
        float2 xr2 = x_l[sub * 4 + 2], xr3 = x_l[sub * 4 + 3];                       \
        _Pragma("unroll")                                                            \
        for (int j = 0; j < 8; ++j) {                                                \
            float4 hr = CRE[j], hi = CIM[j];                                         \
            float sr, si;                                                            \
            sr  = xr0.x * hr.x - xr0.y * hi.x;  si  = xr0.x * hi.x + xr0.y * hr.x;   \
            sr += xr1.x * hr.y - xr1.y * hi.y;  si += xr1.x * hi.y + xr1.y * hr.y;   \
            sr += xr2.x * hr.z - xr2.y * hi.z;  si += xr2.x * hi.z + xr2.y * hr.z;   \
            sr += xr3.x * hr.w - xr3.y * hi.w;  si += xr3.x * hi.w + xr3.y * hr.w;   \
            _Pragma("unroll")                                                        \
            for (int m = 1; m < 32; m <<= 1) {                                       \
                sr += __shfl_xor(sr, m); si += __shfl_xor(si, m);                    \
            }                                                                        \
            if (sub == 0)                                                            \
                st_f2(&partws[par * 4096 + (b * 64 + rbase + 8 * j) * 8 + c],        \
                      make_float2(sr, si));                                          \
        }                                                                            \
        ++ep;                                                                        \
        unsigned* plane = flags + ((ep & 1u) << 9);                                  \
        /* ---- barrier ARRIVE (stores drained by syncthreads) ---- */               \
        __syncthreads();                                                             \
        if (t == 0) st_u(&plane[g * 8], ep);                                         \
        /* ---- overlap zone: prefetch H(blk+1) + tau(blk+1) + y(blk) ---- */        \
        PREF(NRE, NIM, ((blk + 1) & 511));                                           \
        float tau_nxt = 0.0f;                                                        \
        if (t < 64) tau_nxt = ld_f(&tauws[(((blk + 1) & 511) * 8 + b) * 64 + t]);    \
        float yAr, yAi, yBr, yBi;                                                    \
        {                                                                            \
            int b1 = t >> 6, w1 = t & 63, n1 = blk * 64 + w1;                        \
            if (n1 < 16384) { yAr = y_re[b1 * 16384 + n1];         yAi = y_im[b1 * 16384 + n1]; } \
            else            { yAr = y_re[b1 * 16384 + n1 - 16384]; yAi = -y_im[b1 * 16384 + n1 - 16384]; } \
            int i2 = t + 256;                                                        \
            int b2 = i2 >> 6, w2 = i2 & 63, n2 = blk * 64 + w2;                      \
            if (n2 < 16384) { yBr = y_re[b2 * 16384 + n2];         yBi = y_im[b2 * 16384 + n2]; } \
            else            { yBr = y_re[b2 * 16384 + n2 - 16384]; yBi = -y_im[b2 * 16384 + n2 - 16384]; } \
        }                                                                            \
        /* ---- barrier WAIT: every lane polls one WG slot (equality) ---- */        \
        if (t < 64) {                                                                \
            while (ld_u(&plane[t * 8]) != ep) __builtin_amdgcn_s_sleep(1);           \
        }                                                                            \
        __syncthreads();                                                             \
        /* ---- Phase B: reduce partials, r, a2 ---- */                              \
        _Pragma("unroll")                                                            \
        for (int e = 0; e < 2; ++e) {                                                \
            int idx = t + e * 256;                                                   \
            int b1 = idx >> 6, w = idx & 63;                                         \
            const float2* pp = partws + (size_t)par * 4096 + (size_t)idx * 8;        \
            float zr = 0.0f, zi = 0.0f;                                              \
            _Pragma("unroll")                                                        \
            for (int cc = 0; cc < 8; ++cc) {                                         \
                float2 v = ld_f2(pp + cc);                                           \
                zr += v.x; zi += v.y;                                                \
            }                                                                        \
            float rr = ((e == 0) ? yAr : yBr) - zr;                                  \
            float ri = ((e == 0) ? yAi : yBi) - zi;                                  \
            a2s[idx] = rr * rr + ri * ri;                                            \
            if (b1 == b) rown[w] = make_float2(rr, ri);                              \
        }                                                                            \
        __syncthreads();                                                             \
        /* ---- std(global, ddof=1), sigma2(b) ---- */                               \
        float va = a2s[t] + a2s[t + 256];                                            \
        float s_ = wsum64(va);                                                       \
        if (lane == 0) redl[wv] = s_;                                                \
        __syncthreads();                                                             \
        float mean = (redl[0] + redl[1] + redl[2] + redl[3]) * (1.0f / 512.0f);      \
        float d0 = a2s[t] - mean, d1 = a2s[t + 256] - mean;                          \
        float s2_ = wsum64(d0 * d0 + d1 * d1);                                       \
        float sg  = wsum64(a2s[b * 64 + lane]) * (1.0f / 64.0f);                     \
        if (lane == 0) redl[4 + wv] = s2_;                                           \
        __syncthreads();                                                             \
        float stdv = sqrtf((redl[4] + redl[5] + redl[6] + redl[7]) * (1.0f / 511.0f)); \
        if (t < 64) xts[t] = a2s[b * 64 + t] / stdv;                                 \
        __syncthreads();                                                             \
        /* ---- MLP layer 1: 256-thread 4-way k-split (partials in cpartC alias) */  \
        {                                                                            \
            int j = t & 63, q = t >> 6;                                              \
            float acc = 0.0f;                                                        \
            _Pragma("unroll")                                                        \
            for (int k16 = 0; k16 < 16; ++k16) {                                     \
                int k = q * 16 + k16;                                                \
                acc += wTe[k * 64 + j] * xts[k];                                     \
            }                                                                        \
            mpartf[q * 64 + j] = acc;                                                \
        }                                                                            \
        __syncthreads();                                                             \
        if (t < 64) {                                                                \
            float acc = be[t] + mpartf[t] + mpartf[64 + t] + mpartf[128 + t] + mpartf[192 + t]; \
            hts[t] = 1.0f / (1.0f + expf(-acc));                                     \
        }                                                                            \
        __syncthreads();                                                             \
        /* ---- MLP layer 2: update + memory, 4-way k-split ---- */                  \
        {                                                                            \
            int j = t & 63, q = t >> 6;                                              \
            float acc = 0.0f;                                                        \
            _Pragma("unroll")                                                        \
            for (int k16 = 0; k16 < 16; ++k16) {                                     \
                int k = q * 16 + k16;                                                \
                acc += wTu[k * 64 + j] * hts[k] + wTm[k * 64 + j] * taurow[k];       \
            }                                                                        \
            mpartf[q * 64 + j] = acc;                                                \
        }                                                                            \
        __syncthreads();                                                             \
        if (t < 64) {                                                                \
            float tn = bu[t] + bm[t] + mpartf[t] + mpartf[64 + t] + mpartf[128 + t] + mpartf[192 + t]; \
            tn = fmaxf(tn, 0.0f);                                                    \
            if (c == 0) st_f(&tauws[(blk * 8 + b) * 64 + t], tn);                    \
            float2 rv = rown[t];                                                     \
            float scl = tn / sg;                                                     \
            resid[t] = make_float2(rv.x * scl, rv.y * scl);                          \
        }                                                                            \
        __syncthreads();                                                             \
        /* ---- Phase C: x[b, own chunk] += resid @ conj(H) / 65536 (CUR bank) */    \
        float2 ac0 = make_float2(0.f, 0.f), ac1 = make_float2(0.f, 0.f);             \
        float2 ac2 = make_float2(0.f, 0.f), ac3 = make_float2(0.f, 0.f);             \
        _Pragma("unroll")                                                            \
        for (int j = 0; j < 8; ++j) {                                                \
            float2 rs = resid[rbase + 8 * j];                                        \
            float4 hr = CRE[j], hi = CIM[j];                                         \
            ac0.x += rs.x * hr.x + rs.y * hi.x;  ac0.y += rs.y * hr.x - rs.x * hi.x; \
            ac1.x += rs.x * hr.y + rs.y * hi.y;  ac1.y += rs.y * hr.y - rs.x * hi.y; \
            ac2.x += rs.x * hr.z + rs.y * hi.z;  ac2.y += rs.y * hr.z - rs.x * hi.z; \
            ac3.x += rs.x * hr.w + rs.y * hi.w;  ac3.y += rs.y * hr.w - rs.x * hi.w; \
        }                                                                            \
        ac0.x += __shfl_xor(ac0.x, 32); ac0.y += __shfl_xor(ac0.y, 32);              \
        ac1.x += __shfl_xor(ac1.x, 32); ac1.y += __shfl_xor(ac1.y, 32);              \
        ac2.x += __shfl_xor(ac2.x, 32); ac2.y += __shfl_xor(ac2.y, 32);              \
        ac3.x += __shfl_xor(ac3.x, 32); ac3.y += __shfl_xor(ac3.y, 32);              \
        if ((t & 32) == 0) {                                                         \
            cpartC[wv][sub][0] = ac0; cpartC[wv][sub][1] = ac1;                      \
            cpartC[wv][sub][2] = ac2; cpartC[wv][sub][3] = ac3;                      \
        }                                                                            \
        if (t < 64) taurow[t] = tau_nxt;       /* commit prefetched tau */           \
        __syncthreads();                                                             \
        if (t < 128) {                                                               \
            int sl = t >> 2, kk = t & 3;                                             \
            float2 s0 = cpartC[0][sl][kk], s1 = cpartC[1][sl][kk];                   \
            float2 s2 = cpartC[2][sl][kk], s3 = cpartC[3][sl][kk];                   \
            float2 xv = x_l[t];                                                      \
            xv.x += (s0.x + s1.x + s2.x + s3.x) * (1.0f / 65536.0f);                 \
            xv.y += (s0.y + s1.y + s2.y + s3.y) * (1.0f / 65536.0f);                 \
            x_l[t] = xv;                                                             \
        }                                                                            \
    } while (0)

    #pragma unroll 1
    for (int iter = 0; iter < 10; ++iter) {
        #pragma unroll 1
        for (int blk2 = 0; blk2 < 512; blk2 += 2) {
            STEP(blk2,     hAre, hAim, hBre, hBim);
            STEP(blk2 + 1, hBre, hBim, hAre, hAim);
        }

        // ---- soft threshold: x = sgn(x) * relu(|x| - 1e-3 * max|x| (global)) ----
        float lm = 0.0f;
        if (t < 128) { float2 xv = x_l[t]; lm = sqrtf(xv.x * xv.x + xv.y * xv.y); }
        lm = wmax64(lm);
        if (lane == 0) redl[wv] = lm;
        __syncthreads();
        if (t == 0) st_f(&pmws[g], fmaxf(fmaxf(redl[0], redl[1]), fmaxf(redl[2], redl[3])));
        ++ep;
        {
            unsigned* plane = flags + ((ep & 1u) << 9);
            __syncthreads();                     // drain pm (and this WG's tau) stores
            if (t == 0) st_u(&plane[g * 8], ep);
            if (t < 64) {
                while (ld_u(&plane[t * 8]) != ep) __builtin_amdgcn_s_sleep(1);
            }
            __syncthreads();
        }
        float pv = (t < 64) ? ld_f(&pmws[t]) : 0.0f;
        pv = wmax64(pv);
        if (t == 0) gmax[0] = pv;
        __syncthreads();
        float m = gmax[0];
        if (t < 128) {
            float2 xv = x_l[t];
            float ax = sqrtf(xv.x * xv.x + xv.y * xv.y);
            float s = (ax > 0.0f) ? fmaxf(ax - 1e-3f * m, 0.0f) / ax : 0.0f;
            x_l[t] = make_float2(xv.x * s, xv.y * s);
        }
        __syncthreads();
    } // iter

    // ---------------- output ----------------
    if (t < 128) out[b * 1024 + c * 128 + t] = x_l[t].x;
    for (int i = g * 8; i < g * 8 + 8; ++i) {
        for (int idx = t; idx < 512; idx += NT) {
            int bb = idx >> 6, w = idx & 63;
            out[8192 + bb * 32768 + i * 64 + w] = ld_f(&tauws[(i * 8 + bb) * 64 + w]);
        }
    }
#undef STEP
#undef PREF
}

// Diagnostic: if the launch is rejected, stamp the error code into output-0
// as code-distinguishable-through-bf16 multiples of 1e6.
__global__ void robii_diag_kernel(float* out, int code) {
    int i = blockIdx.x * blockDim.x + threadIdx.x;
    if (i < 8192) out[i] = 1.0e6f * (float)(1 + code);
}

extern "C" void kernel_launch(void* const* d_in, const int* in_sizes, int n_in,
                              void* d_out, int out_size, void* d_ws, size_t ws_size,
                              hipStream_t stream) {
    (void)in_sizes; (void)n_in; (void)out_size; (void)ws_size;
    const float* y_re     = (const float*)d_in[0];
    const float* y_im     = (const float*)d_in[1];
    const float* H_re     = (const float*)d_in[2];
    const float* H_im     = (const float*)d_in[3];
    const float* estep_w  = (const float*)d_in[4];
    const float* estep_b  = (const float*)d_in[5];
    const float* update_w = (const float*)d_in[6];
    const float* update_b = (const float*)d_in[7];
    const float* memory_w = (const float*)d_in[8];
    const float* memory_b = (const float*)d_in[9];
    float* outp = (float*)d_out;
    float* wsp  = (float*)d_ws;

    // plain (non-cooperative) launch — 64 blocks on 256 CUs always co-resident
    hipLaunchKernelGGL(robii_kernel, dim3(NWG), dim3(NT), 0, stream,
                       y_re, y_im, H_re, H_im, estep_w, estep_b,
                       update_w, update_b, memory_w, memory_b, outp, wsp);
    hipError_t e = hipGetLastError();
    if (e != hipSuccess) {
        hipLaunchKernelGGL(robii_diag_kernel, dim3(32), dim3(256), 0, stream,
                           outp, (int)e);
    }
}